// Round 1
// baseline (40.156 us; speedup 1.0000x reference)
//
#include <hip/hip_runtime.h>
#include <math.h>

namespace {

constexpr int kNB    = 16;
constexpr int kFrame = 2048;
constexpr int kChunk = 32;   // samples per lane; 64 lanes * 32 = 2048
constexpr int kWPB   = 4;    // waves (= channels) per 256-thread block

__global__ __launch_bounds__(256)
void biquad_chain_kernel(const float* __restrict__ audio,
                         const float* __restrict__ params,
                         float* __restrict__ out)
{
    __shared__ float  sC[kWPB][kNB][5];   // b0, b1, b2, -a1, -a2  (f32)
    __shared__ double sA[kWPB][kNB][2];   // a1, a2                (f64)

    const int tid  = threadIdx.x;
    const int wv   = tid >> 6;
    const int lane = tid & 63;
    const int ch   = blockIdx.x * kWPB + wv;   // 0..2047
    const int bb   = ch >> 7;                  // batch
    const int ff   = ch & 127;                 // frame

    const float* pb = params + (size_t)bb * (50 * 128) + ff;

    // ---- per-channel coefficients: lane i computes band i, in double ----
    if (lane < kNB) {
        const int band = lane;
        const double fn = (double)pb[(band * 3 + 0) * 128];
        const double gn = (double)pb[(band * 3 + 1) * 128];
        const double qn = (double)pb[(band * 3 + 2) * 128];
        const double PI = 3.14159265358979323846;
        const double SR = 96000.0;
        const double Q  = exp(log(0.5) + qn * (log(16.0) - log(0.5)));
        double b0, b1, b2, a0, a1, a2;
        if (band == 0) {                       // HPF, fc in [20, 500] (log)
            const double fc = exp(log(20.0) + fn * (log(500.0) - log(20.0)));
            const double w0 = 2.0 * PI * fc / SR;
            const double al = sin(w0) / (2.0 * Q);
            const double c  = cos(w0);
            b0 = (1.0 + c) * 0.5; b1 = -(1.0 + c); b2 = (1.0 + c) * 0.5;
            a0 = 1.0 + al; a1 = -2.0 * c; a2 = 1.0 - al;
        } else if (band == kNB - 1) {          // LPF, fc in [5000, 20000] (log)
            const double fc = exp(log(5000.0) + fn * (log(20000.0) - log(5000.0)));
            const double w0 = 2.0 * PI * fc / SR;
            const double al = sin(w0) / (2.0 * Q);
            const double c  = cos(w0);
            b0 = (1.0 - c) * 0.5; b1 = 1.0 - c; b2 = (1.0 - c) * 0.5;
            a0 = 1.0 + al; a1 = -2.0 * c; a2 = 1.0 - al;
        } else if (band == 1) {                // low shelf
            const double fc = exp(log(50.0) + fn * (log(16000.0) - log(50.0)));
            const double g  = -24.0 + gn * 48.0;
            const double A  = exp(g * (2.302585092994046 / 40.0)); // 10^(g/40)
            const double w0 = 2.0 * PI * fc / SR;
            const double al = sin(w0) / (2.0 * Q);
            const double c  = cos(w0);
            const double sA2al = 2.0 * sqrt(A) * al;
            b0 = A * ((A + 1.0) - (A - 1.0) * c + sA2al);
            b1 = 2.0 * A * ((A - 1.0) - (A + 1.0) * c);
            b2 = A * ((A + 1.0) - (A - 1.0) * c - sA2al);
            a0 = (A + 1.0) + (A - 1.0) * c + sA2al;
            a1 = -2.0 * ((A - 1.0) + (A + 1.0) * c);
            a2 = (A + 1.0) + (A - 1.0) * c - sA2al;
        } else if (band == kNB - 2) {          // high shelf
            const double fc = exp(log(50.0) + fn * (log(16000.0) - log(50.0)));
            const double g  = -24.0 + gn * 48.0;
            const double A  = exp(g * (2.302585092994046 / 40.0));
            const double w0 = 2.0 * PI * fc / SR;
            const double al = sin(w0) / (2.0 * Q);
            const double c  = cos(w0);
            const double sA2al = 2.0 * sqrt(A) * al;
            b0 = A * ((A + 1.0) + (A - 1.0) * c + sA2al);
            b1 = -2.0 * A * ((A - 1.0) + (A + 1.0) * c);
            b2 = A * ((A + 1.0) + (A - 1.0) * c - sA2al);
            a0 = (A + 1.0) - (A - 1.0) * c + sA2al;
            a1 = 2.0 * ((A - 1.0) - (A + 1.0) * c);
            a2 = (A + 1.0) - (A - 1.0) * c - sA2al;
        } else {                               // peaking, fc in [100, 15000]
            const double fc = exp(log(100.0) + fn * (log(15000.0) - log(100.0)));
            const double g  = -24.0 + gn * 48.0;
            const double A  = exp(g * (2.302585092994046 / 40.0));
            const double w0 = 2.0 * PI * fc / SR;
            const double al = sin(w0) / (2.0 * Q);
            const double c  = cos(w0);
            b0 = 1.0 + al * A; b1 = -2.0 * c; b2 = 1.0 - al * A;
            a0 = 1.0 + al / A; a1 = -2.0 * c; a2 = 1.0 - al / A;
        }
        const double inv = 1.0 / a0;
        b0 *= inv; b1 *= inv; b2 *= inv; a1 *= inv; a2 *= inv;
        sC[wv][band][0] = (float)b0;
        sC[wv][band][1] = (float)b1;
        sC[wv][band][2] = (float)b2;
        sC[wv][band][3] = (float)(-a1);
        sC[wv][band][4] = (float)(-a2);
        sA[wv][band][0] = a1;
        sA[wv][band][1] = a2;
    }
    __syncthreads();

    // broadband in/out gains (rows 48, 49): 10^((-60+60n)/20)
    const float in_g  = (float)exp((-60.0 + (double)pb[48 * 128] * 60.0) * (2.302585092994046 / 20.0));
    const float out_g = (float)exp((-60.0 + (double)pb[49 * 128] * 60.0) * (2.302585092994046 / 20.0));

    // ---- load this lane's 32-sample chunk, apply input gain ----
    float x[kChunk];
    {
        const float4* ap = reinterpret_cast<const float4*>(audio + (size_t)ch * kFrame + lane * kChunk);
        #pragma unroll
        for (int k = 0; k < kChunk / 4; ++k) {
            const float4 v = ap[k];
            x[4 * k + 0] = v.x * in_g;
            x[4 * k + 1] = v.y * in_g;
            x[4 * k + 2] = v.z * in_g;
            x[4 * k + 3] = v.w * in_g;
        }
    }

    // ---- cascade: bands sequential; time parallel via affine chunk scan ----
    for (int band = 0; band < kNB; ++band) {
        const float b0  = sC[wv][band][0];
        const float b1  = sC[wv][band][1];
        const float b2  = sC[wv][band][2];
        const float na1 = sC[wv][band][3];
        const float na2 = sC[wv][band][4];
        const double a1d = sA[wv][band][0];
        const double a2d = sA[wv][band][1];

        // phase 1: zero-state pass over the chunk, keep only final (s1, s2)
        float s1 = 0.f, s2 = 0.f;
        #pragma unroll
        for (int t = 0; t < kChunk; ++t) {
            const float y = fmaf(b0, x[t], s1);
            s1 = fmaf(na1, y, fmaf(b1, x[t], s2));
            s2 = fmaf(na2, y, b2 * x[t]);
        }

        // M = A^32, A = [[-a1, 1], [-a2, 0]]  (f64, 5 squarings)
        double m00 = -a1d, m01 = 1.0, m10 = -a2d, m11 = 0.0;
        #pragma unroll
        for (int s = 0; s < 5; ++s) {
            const double t00 = m00 * m00 + m01 * m10;
            const double t01 = m01 * (m00 + m11);
            const double t10 = m10 * (m00 + m11);
            const double t11 = m10 * m01 + m11 * m11;
            m00 = t00; m01 = t01; m10 = t10; m11 = t11;
        }

        // exclusive affine scan across 64 lanes (Kogge-Stone), f64:
        // u_in(l) = sum_{j<l} M^{l-1-j} d_j
        double v0 = (double)s1, v1 = (double)s2;
        {
            const double e0 = __shfl_up(v0, 1);
            const double e1 = __shfl_up(v1, 1);
            v0 = (lane == 0) ? 0.0 : e0;
            v1 = (lane == 0) ? 0.0 : e1;
        }
        #pragma unroll
        for (int s = 1; s <= 32; s <<= 1) {
            const double t0 = __shfl_up(v0, (unsigned)s);
            const double t1 = __shfl_up(v1, (unsigned)s);
            if (lane >= s) {
                v0 = m00 * t0 + m01 * t1 + v0;
                v1 = m10 * t0 + m11 * t1 + v1;
            }
            if (s < 32) {   // square M for the next distance
                const double t00 = m00 * m00 + m01 * m10;
                const double t01 = m01 * (m00 + m11);
                const double t10 = m10 * (m00 + m11);
                const double t11 = m10 * m01 + m11 * m11;
                m00 = t00; m01 = t01; m10 = t10; m11 = t11;
            }
        }

        // phase 2: re-run chunk with recombined incoming state, emit y in place
        s1 = (float)v0; s2 = (float)v1;
        #pragma unroll
        for (int t = 0; t < kChunk; ++t) {
            const float y = fmaf(b0, x[t], s1);
            s1 = fmaf(na1, y, fmaf(b1, x[t], s2));
            s2 = fmaf(na2, y, b2 * x[t]);
            x[t] = y;
        }
    }

    // ---- store with output gain ----
    {
        float4* op = reinterpret_cast<float4*>(out + (size_t)ch * kFrame + lane * kChunk);
        #pragma unroll
        for (int k = 0; k < kChunk / 4; ++k) {
            float4 v;
            v.x = x[4 * k + 0] * out_g;
            v.y = x[4 * k + 1] * out_g;
            v.z = x[4 * k + 2] * out_g;
            v.w = x[4 * k + 3] * out_g;
            op[k] = v;
        }
    }
}

} // namespace

extern "C" void kernel_launch(void* const* d_in, const int* in_sizes, int n_in,
                              void* d_out, int out_size, void* d_ws, size_t ws_size,
                              hipStream_t stream)
{
    const float* audio  = (const float*)d_in[0];
    const float* params = (const float*)d_in[1];
    float* outp = (float*)d_out;

    const int channels = out_size / kFrame;        // 2048
    const int blocks   = (channels + kWPB - 1) / kWPB;

    hipLaunchKernelGGL(biquad_chain_kernel, dim3(blocks), dim3(256), 0, stream,
                       audio, params, outp);
}

// Round 2
// 32.731 us; speedup vs baseline: 1.2269x; 1.2269x over previous
//
#include <hip/hip_runtime.h>
#include <math.h>

namespace {

constexpr int kNB    = 16;
constexpr int kFrame = 2048;
constexpr int kChunk = 32;   // samples per lane; 64 lanes * 32 = 2048
constexpr int kWPB   = 4;    // waves (= channels) per 256-thread block

__global__ __launch_bounds__(256)
void biquad_chain_kernel(const float* __restrict__ audio,
                         const float* __restrict__ params,
                         float* __restrict__ out)
{
    // per band: b0, b1, b2, -a1, -a2 (f32, gains folded into band 0 / band 15)
    __shared__ float sC[kWPB][kNB][5];
    // per band, per scan level j (matrix A^(32*2^j) = alpha*A + beta*I):
    // [0]=alpha, [1]=beta, [2]=gamma = -a2*alpha
    __shared__ float sLvl[kWPB][kNB][6][3];

    const int tid  = threadIdx.x;
    const int wv   = tid >> 6;
    const int lane = tid & 63;
    const int ch   = blockIdx.x * kWPB + wv;   // 0..2047
    const int bb   = ch >> 7;                  // batch
    const int ff   = ch & 127;                 // frame

    const float* pb = params + (size_t)bb * (50 * 128) + ff;

    // ---- per-channel coefficients: lane i computes band i, in double ----
    if (lane < kNB) {
        const int band = lane;
        const double fn = (double)pb[(band * 3 + 0) * 128];
        const double gn = (double)pb[(band * 3 + 1) * 128];
        const double qn = (double)pb[(band * 3 + 2) * 128];
        const double PI = 3.14159265358979323846;
        const double SR = 96000.0;
        const double LN10 = 2.302585092994046;
        const double Q  = exp(log(0.5) + qn * (log(16.0) - log(0.5)));
        double b0, b1, b2, a0, a1, a2;
        if (band == 0) {                       // HPF, fc in [20, 500] (log)
            const double fc = exp(log(20.0) + fn * (log(500.0) - log(20.0)));
            const double w0 = 2.0 * PI * fc / SR;
            const double al = sin(w0) / (2.0 * Q);
            const double c  = cos(w0);
            b0 = (1.0 + c) * 0.5; b1 = -(1.0 + c); b2 = (1.0 + c) * 0.5;
            a0 = 1.0 + al; a1 = -2.0 * c; a2 = 1.0 - al;
        } else if (band == kNB - 1) {          // LPF, fc in [5000, 20000] (log)
            const double fc = exp(log(5000.0) + fn * (log(20000.0) - log(5000.0)));
            const double w0 = 2.0 * PI * fc / SR;
            const double al = sin(w0) / (2.0 * Q);
            const double c  = cos(w0);
            b0 = (1.0 - c) * 0.5; b1 = 1.0 - c; b2 = (1.0 - c) * 0.5;
            a0 = 1.0 + al; a1 = -2.0 * c; a2 = 1.0 - al;
        } else if (band == 1) {                // low shelf
            const double fc = exp(log(50.0) + fn * (log(16000.0) - log(50.0)));
            const double g  = -24.0 + gn * 48.0;
            const double A  = exp(g * (LN10 / 40.0)); // 10^(g/40)
            const double w0 = 2.0 * PI * fc / SR;
            const double al = sin(w0) / (2.0 * Q);
            const double c  = cos(w0);
            const double sA2al = 2.0 * sqrt(A) * al;
            b0 = A * ((A + 1.0) - (A - 1.0) * c + sA2al);
            b1 = 2.0 * A * ((A - 1.0) - (A + 1.0) * c);
            b2 = A * ((A + 1.0) - (A - 1.0) * c - sA2al);
            a0 = (A + 1.0) + (A - 1.0) * c + sA2al;
            a1 = -2.0 * ((A - 1.0) + (A + 1.0) * c);
            a2 = (A + 1.0) + (A - 1.0) * c - sA2al;
        } else if (band == kNB - 2) {          // high shelf
            const double fc = exp(log(50.0) + fn * (log(16000.0) - log(50.0)));
            const double g  = -24.0 + gn * 48.0;
            const double A  = exp(g * (LN10 / 40.0));
            const double w0 = 2.0 * PI * fc / SR;
            const double al = sin(w0) / (2.0 * Q);
            const double c  = cos(w0);
            const double sA2al = 2.0 * sqrt(A) * al;
            b0 = A * ((A + 1.0) + (A - 1.0) * c + sA2al);
            b1 = -2.0 * A * ((A - 1.0) + (A + 1.0) * c);
            b2 = A * ((A + 1.0) + (A - 1.0) * c - sA2al);
            a0 = (A + 1.0) - (A - 1.0) * c + sA2al;
            a1 = 2.0 * ((A - 1.0) - (A + 1.0) * c);
            a2 = (A + 1.0) - (A - 1.0) * c - sA2al;
        } else {                               // peaking, fc in [100, 15000]
            const double fc = exp(log(100.0) + fn * (log(15000.0) - log(100.0)));
            const double g  = -24.0 + gn * 48.0;
            const double A  = exp(g * (LN10 / 40.0));
            const double w0 = 2.0 * PI * fc / SR;
            const double al = sin(w0) / (2.0 * Q);
            const double c  = cos(w0);
            b0 = 1.0 + al * A; b1 = -2.0 * c; b2 = 1.0 - al * A;
            a0 = 1.0 + al / A; a1 = -2.0 * c; a2 = 1.0 - al / A;
        }
        const double inv = 1.0 / a0;
        b0 *= inv; b1 *= inv; b2 *= inv; a1 *= inv; a2 *= inv;

        // fold broadband in/out gains into the first/last band's b coefs
        if (band == 0) {
            const double in_g = exp((-60.0 + (double)pb[48 * 128] * 60.0) * (LN10 / 20.0));
            b0 *= in_g; b1 *= in_g; b2 *= in_g;
        }
        if (band == kNB - 1) {
            const double out_g = exp((-60.0 + (double)pb[49 * 128] * 60.0) * (LN10 / 20.0));
            b0 *= out_g; b1 *= out_g; b2 *= out_g;
        }

        sC[wv][band][0] = (float)b0;
        sC[wv][band][1] = (float)b1;
        sC[wv][band][2] = (float)b2;
        sC[wv][band][3] = (float)(-a1);
        sC[wv][band][4] = (float)(-a2);

        // Cayley-Hamilton power chain: A^k = al*A + be*I, A^2 = -a1*A - a2*I.
        // Squaring: al' = al*(2*be - a1*al);  be' = be*be - a2*al*al.
        // After squaring s (s=0..9) we hold A^(2^(s+1)); store s=4..9
        // -> A^32, A^64, ..., A^1024 (scan levels 0..5).
        double al = 1.0, be = 0.0;               // A^1
        #pragma unroll
        for (int s = 0; s < 10; ++s) {
            const double aln = al * (2.0 * be - a1 * al);
            const double ben = be * be - a2 * (al * al);
            al = aln; be = ben;
            if (s >= 4) {
                const int lvl = s - 4;
                sLvl[wv][band][lvl][0] = (float)al;
                sLvl[wv][band][lvl][1] = (float)be;
                sLvl[wv][band][lvl][2] = (float)(-a2 * al);
            }
        }
    }
    __syncthreads();

    // ---- load this lane's 32-sample chunk (gain folded into band 0) ----
    float x[kChunk];
    {
        const float4* ap = reinterpret_cast<const float4*>(audio + (size_t)ch * kFrame + lane * kChunk);
        #pragma unroll
        for (int k = 0; k < kChunk / 4; ++k) {
            const float4 v = ap[k];
            x[4 * k + 0] = v.x;
            x[4 * k + 1] = v.y;
            x[4 * k + 2] = v.z;
            x[4 * k + 3] = v.w;
        }
    }

    // ---- cascade: bands sequential; time parallel via affine chunk scan ----
    for (int band = 0; band < kNB; ++band) {
        const float b0  = sC[wv][band][0];
        const float b1  = sC[wv][band][1];
        const float b2  = sC[wv][band][2];
        const float na1 = sC[wv][band][3];
        const float na2 = sC[wv][band][4];

        // phase 1: zero-state pass; store y_zero in place, keep final (s1,s2)
        float s1 = 0.f, s2 = 0.f;
        #pragma unroll
        for (int t = 0; t < kChunk; ++t) {
            const float xv = x[t];
            const float y  = fmaf(b0, xv, s1);
            const float tm = fmaf(b1, xv, s2);
            s2 = fmaf(na2, y, b2 * xv);
            s1 = fmaf(na1, y, tm);
            x[t] = y;
        }

        // exclusive affine scan across 64 lanes (Kogge-Stone), f32 values:
        // u_in(l) = sum_{j<l} M^(l-1-j) d_j,  M = A^32 = alpha*A + beta*I
        float v0, v1;
        {
            const float e0 = __shfl_up(s1, 1);
            const float e1 = __shfl_up(s2, 1);
            v0 = (lane == 0) ? 0.f : e0;
            v1 = (lane == 0) ? 0.f : e1;
        }
        #pragma unroll
        for (int j = 0; j < 6; ++j) {
            const int s = 1 << j;
            const float alpha = sLvl[wv][band][j][0];
            const float beta  = sLvl[wv][band][j][1];
            const float gamma = sLvl[wv][band][j][2];
            float t0 = __shfl_up(v0, (unsigned)s);
            float t1 = __shfl_up(v1, (unsigned)s);
            const bool ok = (lane >= s);
            t0 = ok ? t0 : 0.f;
            t1 = ok ? t1 : 0.f;
            // v += (alpha*A + beta*I) * t ;  A*t = (na1*t0 + t1, na2*t0)
            const float w = fmaf(na1, t0, t1);
            v0 = fmaf(alpha, w,  fmaf(beta, t0, v0));
            v1 = fmaf(gamma, t0, fmaf(beta, t1, v1));
        }

        // phase 2: homogeneous correction  y(t) += [A^t * u_in]_0
        float w0 = v0, w1 = v1;
        #pragma unroll
        for (int t = 0; t < kChunk; ++t) {
            const float c = w0;
            x[t] += c;
            w0 = fmaf(na1, c, w1);
            w1 = na2 * c;
        }
    }

    // ---- store (output gain folded into band 15) ----
    {
        float4* op = reinterpret_cast<float4*>(out + (size_t)ch * kFrame + lane * kChunk);
        #pragma unroll
        for (int k = 0; k < kChunk / 4; ++k) {
            float4 v;
            v.x = x[4 * k + 0];
            v.y = x[4 * k + 1];
            v.z = x[4 * k + 2];
            v.w = x[4 * k + 3];
            op[k] = v;
        }
    }
}

} // namespace

extern "C" void kernel_launch(void* const* d_in, const int* in_sizes, int n_in,
                              void* d_out, int out_size, void* d_ws, size_t ws_size,
                              hipStream_t stream)
{
    (void)d_ws; (void)ws_size; (void)n_in; (void)in_sizes;
    const float* audio  = (const float*)d_in[0];
    const float* params = (const float*)d_in[1];
    float* outp = (float*)d_out;

    const int channels = out_size / kFrame;        // 2048
    const int blocks   = (channels + kWPB - 1) / kWPB;

    hipLaunchKernelGGL(biquad_chain_kernel, dim3(blocks), dim3(256), 0, stream,
                       audio, params, outp);
}